// Round 11
// baseline (1434.715 us; speedup 1.0000x reference)
//
#include <hip/hip_runtime.h>

// LSTM encoder, fully fused persistent kernel — XCD-local L2 exchange,
// r11 = r10 with the vmcnt queues untangled:
//  * polls own a CLEAN vmcnt queue: x(t+1) loads are issued only after the
//    tag check resolves (sched_barrier-pinned), so retry reloads wait ~L2 RT
//    (~300cy) instead of serializing behind 900cy HBM x-loads (in-order vmcnt).
//  * SYNC2/3/4 are raw "s_waitcnt lgkmcnt(0); s_barrier" (they only order
//    LDS) -- no vmcnt(0) drains: x-load residual and publish ACK stay off
//    the barrier path. x-LDS-write moved post-SYNC3.
// Exchange (r9/r10-proven): publish = workgroup-scope relaxed stores
// (write-through L1 -> XCD L2; WRITE_SIZE~0); poll = buffer_inv + volatile
// loads (fresh L2); tags in every word; sc1 escalation after 64 rounds.
// Groups = XCDs (HW_REG_XCC_ID + slot claim; coop launch + 147.7KB LDS =>
// 1 WG/CU => exactly 32 WGs/XCD).
//
// Hazard audit (SYNC2/3/4 all lgkm+barrier, full __syncthreads only in setup):
//  OH: h-stage(t) pre-SYNC2(t); reads(t) pre-SYNC3(t); next stage post-SYNC4(t). OK
//  OX[2]: write OX[(t+1)&1] post-SYNC3(t); read(t+1) pre-SYNC2(t+1);
//    separated by SYNC4(t). Rewrite(t+2) post-SYNC3(t+2) > SYNC2(t+1) > reads(t+1). OK
//  red: spill(t) pre-SYNC3(t); read(t) pre-SYNC4(t); next spill post-SYNC2(t+1). OK
//  hcomm ABA: consumer's tag-(t-1) reads happen-before its tag-t publish,
//    which happens-before any producer's tag-(t+1) overwrite (poll-gated). OK

typedef float  f32x4  __attribute__((ext_vector_type(4)));
typedef __bf16 bf16x8 __attribute__((ext_vector_type(8)));
typedef unsigned short u16x4 __attribute__((ext_vector_type(4)));
typedef unsigned long long u64;

#define TSEQ 512
#define INDIM 300
#define HID 512
#define ESC_ROUNDS 64

// LDS byte offsets
#define OWH 0          // W_hh slice: 64 rows x 1024B
#define OWI 65536      // W_ih slice: 64 rows x 640B (k>=300 zero)
#define OH  106496     // h tile: 16 rows x 1024B (batches 8..15 zero)
#define OX0 122880     // x tile buf0: 16 rows x 640B (pads zero)
#define OX1 133120     // x tile buf1
#define ORED 143360    // C spill: 64*17 f32 = 4352B
#define LDSZ 147712

__device__ __forceinline__ unsigned short f2bf(float f) {
    union { float f; unsigned u; } v; v.f = f;
    unsigned r = v.u + 0x7fffu + ((v.u >> 16) & 1u);  // RNE
    return (unsigned short)(r >> 16);
}
__device__ __forceinline__ float fsigmoid(float x) {
    return 1.0f / (1.0f + __expf(-x));
}
__device__ __forceinline__ float ftanh(float x) {
    float e = __expf(2.0f * x);
    return 1.0f - 2.0f / (e + 1.0f);
}
// Raw LDS-ordering barrier: no vmcnt drain (rule-18 fenced).
__device__ __forceinline__ void lgkm_barrier() {
    asm volatile("s_waitcnt lgkmcnt(0)" ::: "memory");
    __builtin_amdgcn_sched_barrier(0);
    __builtin_amdgcn_s_barrier();
    __builtin_amdgcn_sched_barrier(0);
}

extern "C" __global__ __launch_bounds__(256, 1) void lstm_fused(
    const float* __restrict__ inputs,   // [512][64][300]
    const float* __restrict__ Wih,      // [2048][300]
    const float* __restrict__ Whh,      // [2048][512]
    const float* __restrict__ bih,      // [2048]
    const float* __restrict__ bhh,      // [2048]
    unsigned int* __restrict__ hcomm,   // [2][64][512] (tag<<16)|bf16
    unsigned int* __restrict__ slotcnt, // [8] per-XCD slot counters
    float* __restrict__ out)            // [64][512]
{
    __shared__ __align__(16) char lds[LDSZ];
    __shared__ int slot_sh;

    const int tid = threadIdx.x;

    // ---- discover XCD, claim slot (r7/r9-proven) ----
    int xcd;
    asm("s_getreg_b32 %0, hwreg(HW_REG_XCC_ID)" : "=s"(xcd));
    xcd &= 7;
    if (tid == 0) slot_sh = (int)atomicAdd(&slotcnt[xcd], 1u);

    // ---- zero pad-bearing LDS [OWI, LDSZ) ----
    {
        f32x4 z = {0.0f, 0.0f, 0.0f, 0.0f};
        for (int n = 0; n < 21; ++n) {
            int i = n * 256 + tid;
            if (i < 5136)
                *reinterpret_cast<f32x4*>(lds + OWI + i * 16) = z;
        }
    }
    __syncthreads();
    const int grp = xcd;
    const int mw  = slot_sh & 31;

    // ---- stage W_hh slice (bf16, XOR-swizzled); wave = gate ----
    for (int n = 0; n < 32; ++n) {
        int i  = n * 256 + tid;
        int r  = i >> 7;
        int ic = i & 127;
        int q = r >> 4, jj = r & 15;
        const float4 w = *reinterpret_cast<const float4*>(
            Whh + ((size_t)(q * HID + mw * 16 + jj) * HID + ic * 4));
        u16x4 p = {f2bf(w.x), f2bf(w.y), f2bf(w.z), f2bf(w.w)};
        *reinterpret_cast<u16x4*>(lds + OWH + r * 1024 +
                                  ((ic * 8) ^ ((r & 7) << 4))) = p;
    }
    // ---- stage W_ih slice ----
    for (int n = 0; n < 19; ++n) {
        int i = n * 256 + tid;
        if (i < 4800) {
            int r  = i / 75;
            int ic = i - r * 75;
            int q = r >> 4, jj = r & 15;
            const float4 w = *reinterpret_cast<const float4*>(
                Wih + ((size_t)(q * HID + mw * 16 + jj) * INDIM + ic * 4));
            u16x4 p = {f2bf(w.x), f2bf(w.y), f2bf(w.z), f2bf(w.w)};
            *reinterpret_cast<u16x4*>(lds + OWI + r * 640 +
                                      ((ic * 8) ^ ((r & 7) << 4))) = p;
        }
    }

    // ---- per-thread MFMA roles ----
    const int lane = tid & 63;
    const int wv   = tid >> 6;
    const int arow = wv * 16 + (lane & 15);
    const int kb16 = (lane >> 4) << 4;
    const int amask = (arow & 7) << 4;
    const int aoffh = arow * 1024;
    const int aoffi = arow * 640;
    const int bcol  = lane & 15;
    const int bmask = (bcol & 7) << 4;
    const int boffh = bcol * 1024;
    const int boffi = bcol * 640;

    // assembly roles (tid < 128)
    const int aj = tid & 15;
    const int ab = tid >> 4;
    float bias0 = 0.f, bias1 = 0.f, bias2 = 0.f, bias3 = 0.f;
    if (tid < 128) {
        int hidx = mw * 16 + aj;
        bias0 = bih[0 * HID + hidx] + bhh[0 * HID + hidx];
        bias1 = bih[1 * HID + hidx] + bhh[1 * HID + hidx];
        bias2 = bih[2 * HID + hidx] + bhh[2 * HID + hidx];
        bias3 = bih[3 * HID + hidx] + bhh[3 * HID + hidx];
    }
    float cst = 0.0f;

    // x prefetch decomposition
    const int i0 = tid,       b0 = i0 / 75, c0 = i0 - b0 * 75;
    const int i1 = 256 + tid, b1 = i1 / 75, c1 = i1 - b1 * 75;
    const int i2 = 512 + tid, b2 = i2 / 75, c2 = i2 - b2 * 75;
    const bool has2 = (i2 < 600);

    float* red = reinterpret_cast<float*>(lds + ORED);

    // ---- prologue: stage x_0 into OX0 ----
    {
        const float* xb = inputs + (size_t)(grp * 8) * INDIM;
        float4 v0 = *reinterpret_cast<const float4*>(xb + (size_t)b0 * INDIM + c0 * 4);
        float4 v1 = *reinterpret_cast<const float4*>(xb + (size_t)b1 * INDIM + c1 * 4);
        u16x4 p0 = {f2bf(v0.x), f2bf(v0.y), f2bf(v0.z), f2bf(v0.w)};
        u16x4 p1 = {f2bf(v1.x), f2bf(v1.y), f2bf(v1.z), f2bf(v1.w)};
        *reinterpret_cast<u16x4*>(lds + OX0 + b0 * 640 + ((c0 * 8) ^ ((b0 & 7) << 4))) = p0;
        *reinterpret_cast<u16x4*>(lds + OX0 + b1 * 640 + ((c1 * 8) ^ ((b1 & 7) << 4))) = p1;
        if (has2) {
            float4 v2 = *reinterpret_cast<const float4*>(xb + (size_t)b2 * INDIM + c2 * 4);
            u16x4 p2 = {f2bf(v2.x), f2bf(v2.y), f2bf(v2.z), f2bf(v2.w)};
            *reinterpret_cast<u16x4*>(lds + OX0 + b2 * 640 + ((c2 * 8) ^ ((b2 & 7) << 4))) = p2;
        }
    }
    __syncthreads();   // weights + x_0 staged (full barrier once)

#pragma unroll 1
    for (int t = 0; t < TSEQ; ++t) {
        const char* oxc = lds + OX0 + (t & 1) * 10240;

        // ---- (1) vL1 invalidate + issue 8 h poll loads (CLEAN vmcnt queue) ----
        u64 hv64[8];
        const u64* hc = reinterpret_cast<const u64*>(
            hcomm + (size_t)(t & 1) * 32768) + (size_t)grp * 2048 + tid;
        const volatile u64* hcv = reinterpret_cast<const volatile u64*>(hc);
        if (t > 0) {
            asm volatile("buffer_inv" ::: "memory");
#pragma unroll
            for (int b = 0; b < 8; ++b) hv64[b] = hcv[b * 256];
            __builtin_amdgcn_sched_barrier(0);   // polls stay issued here
        }

        // ---- (2) x-part MFMAs (cover poll latency) ----
        f32x4 ac0 = {0.f, 0.f, 0.f, 0.f};
        f32x4 ac1 = {0.f, 0.f, 0.f, 0.f};
        f32x4 ac2 = {0.f, 0.f, 0.f, 0.f};
        f32x4 ac3 = {0.f, 0.f, 0.f, 0.f};
#pragma unroll
        for (int m = 0; m < 10; ++m) {
            bf16x8 a = *reinterpret_cast<const bf16x8*>(
                lds + OWI + aoffi + ((m * 64 + kb16) ^ amask));
            bf16x8 b = *reinterpret_cast<const bf16x8*>(
                oxc + boffi + ((m * 64 + kb16) ^ bmask));
            switch (m & 3) {
                case 0: ac0 = __builtin_amdgcn_mfma_f32_16x16x32_bf16(a, b, ac0, 0, 0, 0); break;
                case 1: ac1 = __builtin_amdgcn_mfma_f32_16x16x32_bf16(a, b, ac1, 0, 0, 0); break;
                case 2: ac2 = __builtin_amdgcn_mfma_f32_16x16x32_bf16(a, b, ac2, 0, 0, 0); break;
                default: ac3 = __builtin_amdgcn_mfma_f32_16x16x32_bf16(a, b, ac3, 0, 0, 0); break;
            }
        }

        // ---- (3) tag check; parallel retry on a queue with ONLY polls ----
        if (t > 0) {
            const u64 expect = ((u64)t << 48) | ((u64)t << 16);
            const u64 tmask  = 0xffff0000ffff0000ull;
            unsigned pend = 0;
#pragma unroll
            for (int b = 0; b < 8; ++b)
                if ((hv64[b] & tmask) != expect) pend |= 1u << b;
            int rounds = 0;
            while (pend) {
                __builtin_amdgcn_s_sleep(1);
                if (rounds < ESC_ROUNDS) {
                    asm volatile("buffer_inv" ::: "memory");
#pragma unroll
                    for (int b = 0; b < 8; ++b)
                        if (pend & (1u << b)) hv64[b] = hcv[b * 256];
                } else {   // safety net: sc1 probes peer L2s / L3
#pragma unroll
                    for (int b = 0; b < 8; ++b)
                        if (pend & (1u << b))
                            hv64[b] = __hip_atomic_load(hc + b * 256, __ATOMIC_RELAXED,
                                                        __HIP_MEMORY_SCOPE_AGENT);
                }
#pragma unroll
                for (int b = 0; b < 8; ++b)
                    if ((hv64[b] & tmask) == expect) pend &= ~(1u << b);
                ++rounds;
            }
#pragma unroll
            for (int b = 0; b < 8; ++b) {
                unsigned pk = (unsigned)(hv64[b] & 0xffffu) |
                              ((unsigned)((hv64[b] >> 32) & 0xffffu) << 16);
                *reinterpret_cast<unsigned*>(
                    lds + OH + b * 1024 + ((tid * 4) ^ ((b & 7) << 4))) = pk;
            }
        }

        // ---- (4) NOW issue x_{t+1} loads (pinned after the retry loop) ----
        __builtin_amdgcn_sched_barrier(0);
        float4 xv0, xv1, xv2;
        if (t + 1 < TSEQ) {
            const float* xb = inputs + ((size_t)(t + 1) * 64 + grp * 8) * INDIM;
            xv0 = *reinterpret_cast<const float4*>(xb + (size_t)b0 * INDIM + c0 * 4);
            xv1 = *reinterpret_cast<const float4*>(xb + (size_t)b1 * INDIM + c1 * 4);
            if (has2)
                xv2 = *reinterpret_cast<const float4*>(xb + (size_t)b2 * INDIM + c2 * 4);
        }

        lgkm_barrier();   // SYNC2: h(t) staged (LDS only; no vmcnt drain)

        // ---- (5) h-part MFMAs (x loads fly underneath) ----
        if (t > 0) {
#pragma unroll
            for (int m = 0; m < 16; ++m) {
                bf16x8 a = *reinterpret_cast<const bf16x8*>(
                    lds + OWH + aoffh + ((m * 64 + kb16) ^ amask));
                bf16x8 b = *reinterpret_cast<const bf16x8*>(
                    lds + OH + boffh + ((m * 64 + kb16) ^ bmask));
                switch (m & 3) {
                    case 0: ac0 = __builtin_amdgcn_mfma_f32_16x16x32_bf16(a, b, ac0, 0, 0, 0); break;
                    case 1: ac1 = __builtin_amdgcn_mfma_f32_16x16x32_bf16(a, b, ac1, 0, 0, 0); break;
                    case 2: ac2 = __builtin_amdgcn_mfma_f32_16x16x32_bf16(a, b, ac2, 0, 0, 0); break;
                    default: ac3 = __builtin_amdgcn_mfma_f32_16x16x32_bf16(a, b, ac3, 0, 0, 0); break;
                }
            }
        }
        f32x4 accv = (ac0 + ac1) + (ac2 + ac3);

        // ---- (6) spill C (m89 layout: col=lane&15, row=(lane>>4)*4+reg) ----
        {
            int rbase = (wv * 16 + ((lane >> 4) << 2)) * 17 + bcol;
            red[rbase + 0]  = accv.x;
            red[rbase + 17] = accv.y;
            red[rbase + 34] = accv.z;
            red[rbase + 51] = accv.w;
        }

        lgkm_barrier();   // SYNC3: spill visible (LDS only)

        // ---- (7) write x_{t+1} into the other OX buffer (vmcnt wait here,
        //          off the barrier path; ~200cy residual under h-MFMAs) ----
        if (t + 1 < TSEQ) {
            char* oxn = lds + OX0 + ((t + 1) & 1) * 10240;
            u16x4 p0 = {f2bf(xv0.x), f2bf(xv0.y), f2bf(xv0.z), f2bf(xv0.w)};
            u16x4 p1 = {f2bf(xv1.x), f2bf(xv1.y), f2bf(xv1.z), f2bf(xv1.w)};
            *reinterpret_cast<u16x4*>(oxn + b0 * 640 + ((c0 * 8) ^ ((b0 & 7) << 4))) = p0;
            *reinterpret_cast<u16x4*>(oxn + b1 * 640 + ((c1 * 8) ^ ((b1 & 7) << 4))) = p1;
            if (has2) {
                u16x4 p2 = {f2bf(xv2.x), f2bf(xv2.y), f2bf(xv2.z), f2bf(xv2.w)};
                *reinterpret_cast<u16x4*>(oxn + b2 * 640 + ((c2 * 8) ^ ((b2 & 7) << 4))) = p2;
            }
        }

        // ---- (8) gates + cell update + workgroup-scope publish (no drain) ----
        if (tid < 128) {
            float gi = bias0 + red[(0 * 16 + aj) * 17 + ab];
            float gf = bias1 + red[(1 * 16 + aj) * 17 + ab];
            float gg = bias2 + red[(2 * 16 + aj) * 17 + ab];
            float go = bias3 + red[(3 * 16 + aj) * 17 + ab];
            float ig = fsigmoid(gi);
            float fg = fsigmoid(gf);
            float cg = ftanh(gg);
            float og = fsigmoid(go);
            cst = fg * cst + ig * cg;
            float hv = og * ftanh(cst);
            if (t == TSEQ - 1) {
                out[(size_t)(grp * 8 + ab) * HID + mw * 16 + aj] = hv;
            } else {
                unsigned word = ((unsigned)(t + 1) << 16) | (unsigned)f2bf(hv);
                __hip_atomic_store(
                    hcomm + (size_t)((t + 1) & 1) * 32768 +
                        (size_t)(grp * 8 + ab) * 512 + mw * 16 + aj,
                    word, __ATOMIC_RELAXED, __HIP_MEMORY_SCOPE_WORKGROUP);
            }
        }

        lgkm_barrier();   // SYNC4: OX(t+1)/red ordered; publish ACK NOT drained
    }
}

extern "C" void kernel_launch(void* const* d_in, const int* in_sizes, int n_in,
                              void* d_out, int out_size, void* d_ws, size_t ws_size,
                              hipStream_t stream) {
    const float* inputs = (const float*)d_in[0];
    const float* Wih    = (const float*)d_in[1];
    const float* Whh    = (const float*)d_in[2];
    const float* bih    = (const float*)d_in[3];
    const float* bhh    = (const float*)d_in[4];
    float* out = (float*)d_out;

    unsigned int* hcomm   = (unsigned int*)d_ws;                    // 256 KB
    unsigned int* slotcnt = (unsigned int*)((char*)d_ws + 262144);  // 32 B

    hipMemsetAsync(d_ws, 0, 262144 + 64, stream);

    void* args[] = {(void*)&inputs, (void*)&Wih, (void*)&Whh, (void*)&bih,
                    (void*)&bhh,    (void*)&hcomm, (void*)&slotcnt, (void*)&out};
    hipLaunchCooperativeKernel(reinterpret_cast<void*>(lstm_fused),
                               dim3(256), dim3(256), args, 0, stream);
}